// Round 14
// baseline (1857.487 us; speedup 1.0000x reference)
//
#include <hip/hip_runtime.h>
#include <hip/hip_bf16.h>
#include <stdint.h>

#define S_LEN 2048
#define HDIM  3584
#define NHEAD 28
#define NKVH  4
#define HDHD  128
#define IDIM  18944

typedef __attribute__((ext_vector_type(8))) short short8;
typedef __attribute__((ext_vector_type(4))) float floatx4;
typedef __attribute__((ext_vector_type(4))) unsigned int uint4v;

__device__ __forceinline__ unsigned short f2bf(float f) {
  union { float f; unsigned int u; } v; v.f = f;
  unsigned int r = v.u + 0x7fffu + ((v.u >> 16) & 1u);
  return (unsigned short)(r >> 16);
}
__device__ __forceinline__ float bf2f(unsigned short h) {
  union { unsigned int u; float f; } v; v.u = ((unsigned int)h) << 16;
  return v.f;
}
// packed f32x2 -> bf16x2 (RNE); lowers to v_cvt_pk_bf16_f32
__device__ __forceinline__ unsigned int pk2(float a, float b) {
  __hip_bfloat162 h = __float22bfloat162_rn(make_float2(a, b));
  union { __hip_bfloat162 h; unsigned int u; } c; c.h = h; return c.u;
}

__device__ __forceinline__ void gload_lds16(const void* g, void* l) {
  __builtin_amdgcn_global_load_lds(
      (const __attribute__((address_space(1))) void*)g,
      (__attribute__((address_space(3))) void*)l, 16, 0, 0);
}

// XCD-chunked block remap: consecutive logical ids stay on one XCD.
__device__ __forceinline__ int xcd_remap(int id, int total) {
  return (id & 7) * (total >> 3) + (id >> 3);   // total % 8 == 0 for all grids
}

__device__ __forceinline__ void store_out(int MODE, void* outp, const void* aux,
                                          size_t oidx, float v) {
  if (MODE == 0) {
    ((float*)outp)[oidx] = v;
  } else if (MODE == 1) {
    ((unsigned short*)outp)[oidx] = f2bf(v);
  } else if (MODE == 2) {
    ((float*)outp)[oidx] = v + ((const float*)aux)[oidx];
  } else {
    float gt = bf2f(((const unsigned short*)aux)[oidx]);
    float sg = gt / (1.f + __expf(-gt));
    ((unsigned short*)outp)[oidx] = f2bf(sg * v);
  }
}

// ---------------------------------------------------------------------------
// 128x128 GEMM, 4 waves, 32 KB LDS, 3+ blocks/CU (9.9 TB/s staging).
// Best when A streams (down-proj).
// ---------------------------------------------------------------------------
template<int MODE, bool BIAS>
__global__ __launch_bounds__(256)
void gemm_bf(const unsigned short* __restrict__ A, int lda,
             const unsigned short* __restrict__ W,
             const float* __restrict__ bias,
             void* __restrict__ outp, int ldo, int col0,
             const void* __restrict__ aux, int K)
{
  const int g  = xcd_remap(blockIdx.x, gridDim.x);
  const int mb = g & 15;
  const int nb = g >> 4;
  const int t = threadIdx.x;
  const int w = t >> 6, l = t & 63, lg = l >> 4, lc = l & 15;
  const int wr = w >> 1, wc = w & 1;

  __shared__ __align__(16) unsigned short As[128 * 64];
  __shared__ __align__(16) unsigned short Ws[128 * 64];

  floatx4 acc[4][4] = {};

  const char* Ablk = (const char*)(A + (size_t)mb * 128 * lda);
  const char* Wblk = (const char*)(W + (size_t)nb * 128 * K);

  const int s_row = t >> 3;
  const int s_scb = (((t & 7) ^ ((t >> 3) & 7)) << 4);
  const int r_sw  = (lc & 7) << 4;

  const size_t abytes = (size_t)lda * 2;
  const size_t wbytes = (size_t)K * 2;
  const int nk = K >> 6;
  for (int kt = 0; kt < nk; ++kt) {
    #pragma unroll
    for (int i = 0; i < 4; ++i)
      gload_lds16(Ablk + (size_t)(i * 32 + s_row) * abytes + (size_t)kt * 128 + s_scb,
                  (char*)As + i * 4096 + t * 16);
    #pragma unroll
    for (int i = 0; i < 4; ++i)
      gload_lds16(Wblk + (size_t)(i * 32 + s_row) * wbytes + (size_t)kt * 128 + s_scb,
                  (char*)Ws + i * 4096 + t * 16);
    __syncthreads();
    #pragma unroll
    for (int kk = 0; kk < 2; ++kk) {
      short8 afr[4], bfr[4];
      #pragma unroll
      for (int m = 0; m < 4; ++m)
        afr[m] = *(const short8*)((const char*)As + (wr*64 + m*16 + lc) * 128
                                 + ((kk*64 + lg*16) ^ r_sw));
      #pragma unroll
      for (int n = 0; n < 4; ++n)
        bfr[n] = *(const short8*)((const char*)Ws + (wc*64 + n*16 + lc) * 128
                                  + ((kk*64 + lg*16) ^ r_sw));
      #pragma unroll
      for (int m = 0; m < 4; ++m)
        #pragma unroll
        for (int n = 0; n < 4; ++n)
          acc[m][n] = __builtin_amdgcn_mfma_f32_16x16x32_bf16(afr[m], bfr[n], acc[m][n], 0, 0, 0);
    }
    __syncthreads();
  }

  float bv[4] = {0.f, 0.f, 0.f, 0.f};
  if (BIAS) {
    #pragma unroll
    for (int n = 0; n < 4; ++n) bv[n] = bias[nb*128 + wc*64 + n*16 + lc];
  }
  #pragma unroll
  for (int m = 0; m < 4; ++m) {
    #pragma unroll
    for (int n = 0; n < 4; ++n) {
      const int colg = col0 + nb*128 + wc*64 + n*16 + lc;
      #pragma unroll
      for (int j = 0; j < 4; ++j) {
        const int rowg = mb*128 + wr*64 + m*16 + lg*4 + j;
        store_out(MODE, outp, aux, (size_t)rowg * ldo + colg, acc[m][n][j] + bv[n]);
      }
    }
  }
}

// ---------------------------------------------------------------------------
// 256(M)x128(N) GEMM, single-buffered BK=64 (proven R7). QKV, O.
// ---------------------------------------------------------------------------
template<int MODE, bool BIAS>
__global__ __launch_bounds__(256, 2)
void gemm_w(const unsigned short* __restrict__ A, int lda,
            const unsigned short* __restrict__ W,
            const float* __restrict__ bias,
            void* __restrict__ outp, int ldo, int col0,
            const void* __restrict__ aux, int K)
{
  const int g  = xcd_remap(blockIdx.x, gridDim.x);
  const int mb = g & 7;
  const int nb = g >> 3;
  const int t  = threadIdx.x;
  const int w  = t >> 6, l = t & 63, lg = l >> 4, lc = l & 15;
  const int wr = w >> 1, wc = w & 1;

  __shared__ __align__(16) unsigned short As[256 * 64];
  __shared__ __align__(16) unsigned short Bs[128 * 64];

  floatx4 acc[8][4] = {};

  const char* Ablk = (const char*)(A + (size_t)mb * 256 * lda);
  const char* Wblk = (const char*)(W + (size_t)nb * 128 * K);

  const int s_row = t >> 3;
  const int s_scb = (((t & 7) ^ ((t >> 3) & 7)) << 4);
  const int r_sw  = (lc & 7) << 4;

  const size_t abytes = (size_t)lda * 2;
  const size_t wbytes = (size_t)K * 2;
  const int nk = K >> 6;

  for (int kt = 0; kt < nk; ++kt) {
    const char* asrc = Ablk + (size_t)kt * 128 + s_scb;
    #pragma unroll
    for (int i = 0; i < 8; ++i)
      gload_lds16(asrc + (size_t)(i * 32 + s_row) * abytes,
                  (char*)As + i * 4096 + t * 16);
    const char* wsrc = Wblk + (size_t)kt * 128 + s_scb;
    #pragma unroll
    for (int i = 0; i < 4; ++i)
      gload_lds16(wsrc + (size_t)(i * 32 + s_row) * wbytes,
                  (char*)Bs + i * 4096 + t * 16);
    __syncthreads();
    #pragma unroll
    for (int kk = 0; kk < 2; ++kk) {
      const int ko = (kk * 64 + lg * 16) ^ r_sw;
      short8 bfr[4];
      #pragma unroll
      for (int n = 0; n < 4; ++n)
        bfr[n] = *(const short8*)((const char*)Bs + (wc*64 + n*16 + lc) * 128 + ko);
      #pragma unroll
      for (int m = 0; m < 8; ++m) {
        short8 af = *(const short8*)((const char*)As + (wr*128 + m*16 + lc) * 128 + ko);
        #pragma unroll
        for (int n = 0; n < 4; ++n)
          acc[m][n] = __builtin_amdgcn_mfma_f32_16x16x32_bf16(af, bfr[n], acc[m][n], 0, 0, 0);
      }
    }
    __syncthreads();
  }

  float bv[4] = {0.f, 0.f, 0.f, 0.f};
  if (BIAS) {
    #pragma unroll
    for (int n = 0; n < 4; ++n) bv[n] = bias[nb*128 + wc*64 + n*16 + lc];
  }
  #pragma unroll
  for (int m = 0; m < 8; ++m) {
    #pragma unroll
    for (int n = 0; n < 4; ++n) {
      const int colg = col0 + nb*128 + wc*64 + n*16 + lc;
      #pragma unroll
      for (int j = 0; j < 4; ++j) {
        const int rowg = mb*256 + wr*128 + m*16 + lg*4 + j;
        store_out(MODE, outp, aux, (size_t)rowg * ldo + colg, acc[m][n][j] + bv[n]);
      }
    }
  }
}

// ---------------------------------------------------------------------------
// m201-faithful 8-phase 256x256 GEMM. 512 thr / 8 waves (wr 0..1 row-band,
// wc 0..3 col-band), BK=64, 2 K-tiles per iteration, 128 KB LDS:
// A[par][half][128][64], B[par][half][128][64] (par = K-tile parity).
// Per phase: [ds_reads][stage 1 half (2 gloads)][vmcnt(4) @P4,P8 only]
// [barrier][lgkm(0)][16 MFMA][barrier]. Slot lifetimes (B dead after P2/P6,
// A after P3/P7) make every stage target a dead slot >=1 phase after its
// last read (WAR-safe via double barrier); every staged half has >=2 stages
// issued after it before its vmcnt(4) guarantee point (RAW-safe).
// Tail: out-of-range stage targets remap to tiles 0/1 (same parity, dead
// slots) so vmcnt counting stays uniform. Prologue: 6 stages + vmcnt(0).
// ---------------------------------------------------------------------------
#define RD_A(par, mu)                                                          \
  do {                                                                         \
    const char* _b = (const char*)Ab[par][wr];                                 \
    _Pragma("unroll")                                                          \
    for (int m = 0; m < 4; ++m)                                                \
      _Pragma("unroll")                                                        \
      for (int kk = 0; kk < 2; ++kk)                                           \
        af[m][kk] = *(const short8*)(_b + ((mu)*64 + m*16 + lc) * 128          \
                                     + ((kk*64 + lg*16) ^ r_sw));              \
  } while (0)

#define RD_B(par, nu, bf)                                                      \
  do {                                                                         \
    const char* _b = (const char*)Bb[par][bh];                                 \
    _Pragma("unroll")                                                          \
    for (int n = 0; n < 2; ++n)                                                \
      _Pragma("unroll")                                                        \
      for (int kk = 0; kk < 2; ++kk)                                           \
        bf[n][kk] = *(const short8*)(_b + (brl + (nu)*32 + n*16 + lc) * 128    \
                                     + ((kk*64 + lg*16) ^ r_sw));              \
  } while (0)

#define MFMA16(mu, nu, bf)                                                     \
  do {                                                                         \
    __builtin_amdgcn_s_setprio(1);                                             \
    _Pragma("unroll")                                                          \
    for (int m = 0; m < 4; ++m)                                                \
      _Pragma("unroll")                                                        \
      for (int n = 0; n < 2; ++n)                                              \
        _Pragma("unroll")                                                      \
        for (int kk = 0; kk < 2; ++kk)                                         \
          acc[mu][nu][m][n] = __builtin_amdgcn_mfma_f32_16x16x32_bf16(         \
              af[m][kk], bf[n][kk], acc[mu][nu][m][n], 0, 0, 0);               \
    __builtin_amdgcn_s_setprio(0);                                             \
  } while (0)

#define PH_BAR()                                                               \
  do {                                                                         \
    __builtin_amdgcn_sched_barrier(0);                                         \
    __builtin_amdgcn_s_barrier();                                              \
    asm volatile("s_waitcnt lgkmcnt(0)" ::: "memory");                         \
    __builtin_amdgcn_sched_barrier(0);                                         \
  } while (0)

#define PH_END()                                                               \
  do {                                                                         \
    __builtin_amdgcn_sched_barrier(0);                                         \
    __builtin_amdgcn_s_barrier();                                              \
    __builtin_amdgcn_sched_barrier(0);                                         \
  } while (0)

template<int MODE>
__global__ __launch_bounds__(512)
void gemm_8p2(const unsigned short* __restrict__ A, int lda,
              const unsigned short* __restrict__ W,
              void* __restrict__ outp, int ldo,
              const void* __restrict__ aux, int K)
{
  const int g  = xcd_remap(blockIdx.x, gridDim.x);
  const int mb = g & 7;
  const int nb = g >> 3;
  const int t  = threadIdx.x;
  const int w  = t >> 6, l = t & 63, lg = l >> 4, lc = l & 15;
  const int wr  = w >> 2;         // 0..1: 128-row band
  const int wc  = w & 3;          // 0..3: 64-col band
  const int bh  = wc >> 1;        // B half owned by this wave
  const int brl = (wc & 1) * 64;  // row base inside B half

  __shared__ __align__(16) unsigned short Ab[2][2][128 * 64];  // 64 KB
  __shared__ __align__(16) unsigned short Bb[2][2][128 * 64];  // 64 KB

  floatx4 acc[2][2][4][2] = {};   // [mu][nu][m][n]

  const char* Ablk = (const char*)(A + (size_t)mb * 256 * lda);
  const char* Wblk = (const char*)(W + (size_t)nb * 256 * K);

  const int srow = t >> 3;                               // 0..63
  const int scb  = (((t & 7) ^ ((t >> 3) & 7)) << 4);    // pre-swizzled src
  const int r_sw = (lc & 7) << 4;

  const size_t ab = (size_t)lda * 2;
  const size_t wb2 = (size_t)K * 2;

  auto stage_a = [&](int par, int half, int kt) {
    const char* src = Ablk + (size_t)(half * 128) * ab + (size_t)kt * 128 + scb;
    char* dst = (char*)Ab[par][half] + t * 16;
    gload_lds16(src + (size_t)srow * ab, dst);
    gload_lds16(src + (size_t)(64 + srow) * ab, dst + 8192);
  };
  auto stage_b = [&](int par, int half, int kt) {
    const char* src = Wblk + (size_t)(half * 128) * wb2 + (size_t)kt * 128 + scb;
    char* dst = (char*)Bb[par][half] + t * 16;
    gload_lds16(src + (size_t)srow * wb2, dst);
    gload_lds16(src + (size_t)(64 + srow) * wb2, dst + 8192);
  };

  const int NT = K >> 6;          // 56 for K=3584 (even)
  // prologue: tile0 fully (par0), tile1 B halves (par1)
  stage_b(0, 0, 0); stage_b(0, 1, 0); stage_a(0, 0, 0); stage_a(0, 1, 0);
  stage_b(1, 0, 1); stage_b(1, 1, 1);
  asm volatile("s_waitcnt vmcnt(0)" ::: "memory");
  __builtin_amdgcn_sched_barrier(0);
  __builtin_amdgcn_s_barrier();
  __builtin_amdgcn_sched_barrier(0);

  short8 af[4][2], b0[2][2], b1[2][2];

  for (int j = 0; j < (NT >> 1); ++j) {
    const int t1 = 2 * j + 1;                            // always real
    const int t2 = (2 * j + 2 < NT) ? (2 * j + 2) : 0;   // dummy -> tile0 (par0)
    const int t3 = (2 * j + 3 < NT) ? (2 * j + 3) : 1;   // dummy -> tile1 (par1)

    // P1: T0 (mu0,nu0). stage A0[par1] <- t1 (A[par1] dead since prev P7)
    RD_A(0, 0); RD_B(0, 0, b0);
    stage_a(1, 0, t1);
    PH_BAR(); MFMA16(0, 0, b0); PH_END();

    // P2: T0 (mu0,nu1). stage A1[par1] <- t1
    RD_B(0, 1, b1);
    stage_a(1, 1, t1);
    PH_BAR(); MFMA16(0, 1, b1); PH_END();

    // P3: T0 (mu1,nu1). stage B0[par0] <- t2 (B[par0] dead since P2)
    RD_A(0, 1);
    stage_b(0, 0, t2);
    PH_BAR(); MFMA16(1, 1, b1); PH_END();

    // P4: T0 (mu1,nu0). stage B1[par0] <- t2. vmcnt(4).
    stage_b(0, 1, t2);
    asm volatile("s_waitcnt vmcnt(4)" ::: "memory");
    PH_BAR(); MFMA16(1, 0, b0); PH_END();

    // P5: T1 (mu0,nu0). stage A0[par0] <- t2 (A[par0] dead since P3)
    RD_A(1, 0); RD_B(1, 0, b0);
    stage_a(0, 0, t2);
    PH_BAR(); MFMA16(0, 0, b0); PH_END();

    // P6: T1 (mu0,nu1). stage A1[par0] <- t2
    RD_B(1, 1, b1);
    stage_a(0, 1, t2);
    PH_BAR(); MFMA16(0, 1, b1); PH_END();

    // P7: T1 (mu1,nu1). stage B0[par1] <- t3 (B[par1] dead since P6)
    RD_A(1, 1);
    stage_b(1, 0, t3);
    PH_BAR(); MFMA16(1, 1, b1); PH_END();

    // P8: T1 (mu1,nu0). stage B1[par1] <- t3. vmcnt(4).
    stage_b(1, 1, t3);
    asm volatile("s_waitcnt vmcnt(4)" ::: "memory");
    PH_BAR(); MFMA16(1, 0, b0); PH_END();
  }

  #pragma unroll
  for (int mu = 0; mu < 2; ++mu)
    #pragma unroll
    for (int nu = 0; nu < 2; ++nu)
      #pragma unroll
      for (int m = 0; m < 4; ++m)
        #pragma unroll
        for (int n = 0; n < 2; ++n) {
          const int colg = nb*256 + bh*128 + brl + nu*32 + n*16 + lc;
          #pragma unroll
          for (int jj = 0; jj < 4; ++jj) {
            const int rowg = mb*256 + wr*128 + mu*64 + m*16 + lg*4 + jj;
            store_out(MODE, outp, aux, (size_t)rowg * ldo + colg, acc[mu][nu][m][n][jj]);
          }
        }
}

// ---------------------------------------------------------------------------
__global__ __launch_bounds__(256)
void cvt_bf16_kernel(const float* __restrict__ in, unsigned short* __restrict__ out, int n8)
{
  int i = blockIdx.x * 256 + threadIdx.x;
  const int stride = gridDim.x * 256;
  for (; i < n8; i += stride) {
    floatx4 a = *(const floatx4*)(in + (size_t)i * 8);
    floatx4 b = *(const floatx4*)(in + (size_t)i * 8 + 4);
    uint4v p;
    p[0] = pk2(a[0], a[1]); p[1] = pk2(a[2], a[3]);
    p[2] = pk2(b[0], b[1]); p[3] = pk2(b[2], b[3]);
    *(uint4v*)(out + (size_t)i * 8) = p;
  }
}

__global__ void pack_bias_kernel(const float* __restrict__ qb, const float* __restrict__ kb,
                                 const float* __restrict__ vb, float* __restrict__ o)
{
  int i = blockIdx.x * 256 + threadIdx.x;   // 4608
  if (i < 3584) o[i] = qb[i];
  else if (i < 4096) o[i] = kb[i - 3584];
  else if (i < 4608) o[i] = vb[i - 4096];
}

// ---------------------------------------------------------------------------
__global__ __launch_bounds__(448)
void rmsnorm_kernel(const float* __restrict__ x, const float* __restrict__ wgt,
                    unsigned short* __restrict__ out)
{
  const int row = blockIdx.x, t = threadIdx.x;
  const float* xp = x + (size_t)row * HDIM + t * 8;
  floatx4 a = *(const floatx4*)xp;
  floatx4 b = *(const floatx4*)(xp + 4);
  float ss = a[0]*a[0]+a[1]*a[1]+a[2]*a[2]+a[3]*a[3]
           + b[0]*b[0]+b[1]*b[1]+b[2]*b[2]+b[3]*b[3];
  #pragma unroll
  for (int mk = 1; mk < 64; mk <<= 1) ss += __shfl_xor(ss, mk, 64);
  __shared__ float wsum[8];
  if ((t & 63) == 0) wsum[t >> 6] = ss;
  __syncthreads();
  float tot = 0.f;
  #pragma unroll
  for (int i = 0; i < 7; ++i) tot += wsum[i];
  const float sc = rsqrtf(tot * (1.f / 3584.f) + 1e-6f);
  const float* wp = wgt + t * 8;
  short8 o;
  #pragma unroll
  for (int e = 0; e < 4; ++e) o[e]   = (short)f2bf(a[e] * sc * wp[e]);
  #pragma unroll
  for (int e = 0; e < 4; ++e) o[4+e] = (short)f2bf(b[e] * sc * wp[4+e]);
  *(short8*)(out + (size_t)row * HDIM + t * 8) = o;
}

// ---------------------------------------------------------------------------
__global__ void rope_table_kernel(const int* __restrict__ pos, float* __restrict__ tab)
{
  int idx = blockIdx.x * 256 + threadIdx.x;
  int s = idx >> 6, d = idx & 63;
  float p = (float)pos[s];
  float inv = expf(-((float)(2 * d) * (1.f / 128.f)) * 13.815510557964274f);
  float ang = p * inv;
  tab[idx] = cosf(ang);
  tab[S_LEN * 64 + idx] = sinf(ang);
}

template<int NHX>
__global__ void rope_apply_kernel(const float* __restrict__ in, const float* __restrict__ tab,
                                  unsigned short* __restrict__ out, int col0)
{
  int idx = blockIdx.x * 256 + threadIdx.x;
  int d = idx & 63;
  int rem = idx >> 6;
  int hh = rem % NHX;
  int s  = rem / NHX;
  const float* ip = in + (size_t)s * 4608 + col0 + hh * HDHD;
  float x1 = ip[d], x2 = ip[64 + d];
  float c  = tab[s * 64 + d];
  float sn = tab[S_LEN * 64 + s * 64 + d];
  unsigned short* op = out + (size_t)s * (NHX * HDHD) + hh * HDHD;
  op[d]      = f2bf(x1 * c - x2 * sn);
  op[64 + d] = f2bf(x2 * c + x1 * sn);
}

__global__ void vtrans_kernel(const float* __restrict__ qkvf, unsigned short* __restrict__ vt)
{
  int idx = blockIdx.x * 256 + threadIdx.x;
  int s = idx & (S_LEN - 1);
  int c = idx >> 11;
  vt[idx] = f2bf(qkvf[(size_t)s * 4608 + 4096 + c]);
}

// ---------------------------------------------------------------------------
// Flash attention QBLK=128, 512 threads / 8 waves (R10-proven).
// ---------------------------------------------------------------------------
__global__ __launch_bounds__(512)
void attn_kernel(const unsigned short* __restrict__ Q,
                 const unsigned short* __restrict__ Kr,
                 const unsigned short* __restrict__ Vt,
                 unsigned short* __restrict__ O)
{
  const int g  = xcd_remap(blockIdx.x, gridDim.x);   // grid 448
  const int qb = g & 15;
  const int h  = g >> 4;
  const int kvh = h / 7;
  const int t = threadIdx.x, w = t >> 6, l = t & 63, lg = l >> 4, lc = l & 15;

  __shared__ __align__(16) unsigned short Ks[64 * 128];
  __shared__ __align__(16) unsigned short Vs[128 * 64];
  __shared__ __align__(16) unsigned short Ps[8][16 * 64];

  const int qrow = qb * 128 + w * 16 + lc;
  short8 qf[4];
  {
    const unsigned short* qp = Q + (size_t)qrow * HDIM + h * HDHD + lg * 8;
    #pragma unroll
    for (int kk = 0; kk < 4; ++kk) qf[kk] = *(const short8*)(qp + kk * 32);
  }

  float mrun[4], lrun[4];
  #pragma unroll
  for (int j = 0; j < 4; ++j) { mrun[j] = -1e30f; lrun[j] = 0.f; }
  floatx4 oacc[8] = {};

  const int k_row = t >> 4;
  const int k_scb = (((t & 15) ^ ((t >> 4) & 7)) << 4);
  const int v_row = t >> 3;
  const int v_scb = (((t & 7) ^ ((t >> 3) & 7)) << 4);
  const int r_sw  = (lc & 7) << 4;
  const float scale = 0.08838834764831843f;

  for (int kt = 0; kt < 32; ++kt) {
    #pragma unroll
    for (int i = 0; i < 2; ++i)
      gload_lds16((const char*)Kr + ((size_t)(kt*64 + i*32 + k_row) * 512 + kvh*128) * 2 + k_scb,
                  (char*)Ks + i * 8192 + t * 16);
    #pragma unroll
    for (int i = 0; i < 2; ++i)
      gload_lds16((const char*)Vt + ((size_t)(kvh*128 + i*64 + v_row) * S_LEN) * 2
                      + (size_t)kt * 128 + v_scb,
                  (char*)Vs + i * 8192 + t * 16);
    __syncthreads();

    floatx4 sacc[4] = {};
    #pragma unroll
    for (int kk = 0; kk < 4; ++kk) {
      #pragma unroll
      for (int n = 0; n < 4; ++n) {
        short8 kf = *(const short8*)((const char*)Ks + (n*16 + lc) * 256
                                     + ((kk*64 + lg*16) ^ r_sw));
        sacc[n] = __builtin_amdgcn_mfma_f32_16x16x32_bf16(qf[kk], kf, sacc[n], 0, 0, 0);
      }
    }

    float pv[4][4], mt[4];
    #pragma unroll
    for (int j = 0; j < 4; ++j) {
      float a0 = sacc[0][j]*scale, a1 = sacc[1][j]*scale;
      float a2 = sacc[2][j]*scale, a3 = sacc[3][j]*scale;
      pv[0][j]=a0; pv[1][j]=a1; pv[2][j]=a2; pv[3][j]=a3;
      mt[j] = fmaxf(fmaxf(a0, a1), fmaxf(a2, a3));
    }
    #pragma unroll
    for (int mk = 1; mk < 16; mk <<= 1)
      #pragma unroll
      for (int j = 0; j < 4; ++j)
        mt[j] = fmaxf(mt[j], __shfl_xor(mt[j], mk, 16));

    float corr[4], rs[4];
    #pragma unroll
    for (int j = 0; j < 4; ++j) {
      float mn = fmaxf(mrun[j], mt[j]);
      corr[j] = __expf(mrun[j] - mn);
      mrun[j] = mn;
      rs[j] = 0.f;
    }
    #pragma unroll
    for (int n = 0; n < 4; ++n)
      #pragma unroll
      for (int j = 0; j < 4; ++j) {
        float p = __expf(pv[n][j] - mrun[j]);
        pv[n][j] = p; rs[j] += p;
      }
    #pragma unroll
    for (int mk = 1; mk < 16; mk <<= 1)
      #pragma unroll
      for (int j = 0; j < 4; ++j)
        rs[j] += __shfl_xor(rs[j], mk, 16);
    #pragma unroll
    for (int j = 0; j < 4; ++j) lrun[j] = lrun[j] * corr[j] + rs[j];
    #pragma unroll
    for (int q = 0; q < 8; ++q) {
      oacc[q][0] *= corr[0]; oacc[q][1] *= corr[1];
      oacc[q][2] *= corr[2]; oacc[q][3] *= corr[3];
    }

    char* pw = (char*)Ps[w];
    #pragma unroll
    for (int n = 0; n < 4; ++n)
      #pragma unroll
      for (int j = 0; j < 4; ++j) {
        const int prow = lg*4 + j;
        *(unsigned short*)(pw + prow*128 + ((((n*16 + lc)*2)) ^ ((prow & 7) << 4)))
            = f2bf(pv[n][j]);
      }

    short8 pa[2];
    #pragma unroll
    for (int ks = 0; ks < 2; ++ks)
      pa[ks] = *(const short8*)(pw + lc*128 + ((ks*64 + lg*16) ^ r_sw));
    #pragma unroll
    for (int ks = 0; ks < 2; ++ks)
      #pragma unroll
      for (int q = 0; q < 8; ++q) {
        short8 vf = *(const short8*)((const char*)Vs + (q*16 + lc) * 128
                                     + ((ks*64 + lg*16) ^ r_sw));
        oacc[q] = __builtin_amdgcn_mfma_f32_16x16x32_bf16(pa[ks], vf, oacc[q], 0, 0, 0);
      }
    __syncthreads();
  }

  float invl[4];
  #pragma unroll
  for (int j = 0; j < 4; ++j) invl[j] = 1.f / lrun[j];
  #pragma unroll
  for (int q = 0; q < 8; ++q)
    #pragma unroll
    for (int j = 0; j < 4; ++j) {
      int rowg = qb*128 + w*16 + lg*4 + j;
      int colg = h*HDHD + q*16 + lc;
      O[(size_t)rowg * HDIM + colg] = f2bf(oacc[q][j] * invl[j]);
    }
}

__global__ void sentinel_kernel(float* out, int n) {
  int i = blockIdx.x * 256 + threadIdx.x;
  if (i < n) out[i] = 1.0e6f;
}

// ---------------------------------------------------------------------------
extern "C" void kernel_launch(void* const* d_in, const int* in_sizes, int n_in,
                              void* d_out, int out_size, void* d_ws, size_t ws_size,
                              hipStream_t stream)
{
  (void)in_sizes; (void)n_in;
  const float* hidden = (const float*)d_in[0];
  const int*   pos    = (const int*)d_in[1];
  const float* q_w    = (const float*)d_in[2];
  const float* q_b    = (const float*)d_in[3];
  const float* k_w    = (const float*)d_in[4];
  const float* k_b    = (const float*)d_in[5];
  const float* v_w    = (const float*)d_in[6];
  const float* v_b    = (const float*)d_in[7];
  const float* o_w    = (const float*)d_in[8];
  const float* gate_w = (const float*)d_in[9];
  const float* up_w   = (const float*)d_in[10];
  const float* down_w = (const float*)d_in[11];
  const float* ln1    = (const float*)d_in[12];
  const float* ln2    = (const float*)d_in[13];
  float* out = (float*)d_out;
  char* ws = (char*)d_ws;

  unsigned short* XN    = (unsigned short*)(ws + 0);          // S*H bf16
  float*          QKVF  = (float*)(ws + 14680064);            // S*4608 f32
  unsigned short* QR    = (unsigned short*)(ws + 52428800);   // S*3584 bf16
  unsigned short* KR    = (unsigned short*)(ws + 67108864);   // S*512 bf16
  unsigned short* VT    = (unsigned short*)(ws + 69206016);   // 512*S bf16
  float*          ROPET = (float*)(ws + 71303168);            // S*128 f32
  float*          BQKV  = (float*)(ws + 72351744);            // 4608 f32
  unsigned short* CTX   = (unsigned short*)(ws + 77594624);   // S*H bf16
  unsigned short* GBUF  = (unsigned short*)(ws + 0);          // S*I bf16 (phase 2)
  unsigned short* ACT   = (unsigned short*)(ws + 77594624);   // S*I bf16 (phase 2)
  float*          H1    = (float*)(ws + 155189248);           // S*H f32
  unsigned short* XN2   = (unsigned short*)(ws + 184549376);  // S*H bf16
  unsigned short* WB    = (unsigned short*)(ws + 199229440);  // 18944*3584 bf16 (reused)
  const size_t NEED_BIG = 199229440 + 135790592;              // 335,020,032

  if (ws_size < NEED_BIG) {
    sentinel_kernel<<<(out_size + 255) / 256, 256, 0, stream>>>(out, out_size);
    return;
  }

  const int CVG = 2048;

  rope_table_kernel<<<(S_LEN * 64) / 256, 256, 0, stream>>>(pos, ROPET);
  rmsnorm_kernel<<<S_LEN, 448, 0, stream>>>(hidden, ln1, XN);

  pack_bias_kernel<<<18, 256, 0, stream>>>(q_b, k_b, v_b, BQKV);
  cvt_bf16_kernel<<<CVG, 256, 0, stream>>>(q_w, WB,               (3584 * 3584) / 8);
  cvt_bf16_kernel<<<CVG, 256, 0, stream>>>(k_w, WB + 3584 * 3584, (512 * 3584) / 8);
  cvt_bf16_kernel<<<CVG, 256, 0, stream>>>(v_w, WB + 4096 * 3584, (512 * 3584) / 8);

  // QKV: [2048,4608]  gemm_w 8x36 = 288 blocks
  gemm_w<0, true><<<288, 256, 0, stream>>>(XN, HDIM, WB, BQKV, QKVF, 4608, 0, nullptr, HDIM);

  rope_apply_kernel<28><<<(S_LEN * 28 * 64) / 256, 256, 0, stream>>>(QKVF, ROPET, QR, 0);
  rope_apply_kernel<4><<<(S_LEN * 4 * 64) / 256,  256, 0, stream>>>(QKVF, ROPET, KR, 3584);
  vtrans_kernel<<<(512 * S_LEN) / 256, 256, 0, stream>>>(QKVF, VT);

  cvt_bf16_kernel<<<CVG, 256, 0, stream>>>(o_w, WB, (3584 * 3584) / 8);

  // attention: QBLK=128, 512 threads, 448 blocks
  attn_kernel<<<448, 512, 0, stream>>>(QR, KR, VT, CTX);

  // O-proj fused with residual: H1 = CTX*o_w^T + hidden
  gemm_w<2, false><<<224, 256, 0, stream>>>(CTX, HDIM, WB, nullptr, H1, HDIM, 0, hidden, HDIM);
  rmsnorm_kernel<<<S_LEN, 448, 0, stream>>>(H1, ln2, XN2);

  // gate: [2048,18944]  8-phase 256x256, 8x74 = 592 blocks
  cvt_bf16_kernel<<<CVG, 256, 0, stream>>>(gate_w, WB, (IDIM * HDIM) / 8);
  gemm_8p2<1><<<592, 512, 0, stream>>>(XN2, HDIM, WB, GBUF, IDIM, nullptr, HDIM);

  // up + swiglu: [2048,18944]  8-phase 256x256
  cvt_bf16_kernel<<<CVG, 256, 0, stream>>>(up_w, WB, (IDIM * HDIM) / 8);
  gemm_8p2<3><<<592, 512, 0, stream>>>(XN2, HDIM, WB, ACT, IDIM, GBUF, HDIM);

  // down + residual: [2048,3584], K=18944  gemm_bf 448 blocks
  cvt_bf16_kernel<<<CVG, 256, 0, stream>>>(down_w, WB, (HDIM * IDIM) / 8);
  gemm_bf<2, false><<<448, 256, 0, stream>>>(ACT, IDIM, WB, nullptr, out, HDIM, 0, H1, IDIM);
}

// Round 15
// 1650.923 us; speedup vs baseline: 1.1251x; 1.1251x over previous
//
#include <hip/hip_runtime.h>
#include <hip/hip_bf16.h>
#include <stdint.h>

#define S_LEN 2048
#define HDIM  3584
#define NHEAD 28
#define NKVH  4
#define HDHD  128
#define IDIM  18944

typedef __attribute__((ext_vector_type(8))) short short8;
typedef __attribute__((ext_vector_type(4))) float floatx4;
typedef __attribute__((ext_vector_type(4))) unsigned int uint4v;

__device__ __forceinline__ unsigned short f2bf(float f) {
  union { float f; unsigned int u; } v; v.f = f;
  unsigned int r = v.u + 0x7fffu + ((v.u >> 16) & 1u);
  return (unsigned short)(r >> 16);
}
__device__ __forceinline__ float bf2f(unsigned short h) {
  union { unsigned int u; float f; } v; v.u = ((unsigned int)h) << 16;
  return v.f;
}
// packed f32x2 -> bf16x2 (RNE); lowers to v_cvt_pk_bf16_f32
__device__ __forceinline__ unsigned int pk2(float a, float b) {
  __hip_bfloat162 h = __float22bfloat162_rn(make_float2(a, b));
  union { __hip_bfloat162 h; unsigned int u; } c; c.h = h; return c.u;
}

__device__ __forceinline__ void gload_lds16(const void* g, void* l) {
  __builtin_amdgcn_global_load_lds(
      (const __attribute__((address_space(1))) void*)g,
      (__attribute__((address_space(3))) void*)l, 16, 0, 0);
}

// XCD-chunked block remap: consecutive logical ids stay on one XCD.
__device__ __forceinline__ int xcd_remap(int id, int total) {
  return (id & 7) * (total >> 3) + (id >> 3);   // total % 8 == 0 for all grids
}

__device__ __forceinline__ void store_out(int MODE, void* outp, const void* aux,
                                          size_t oidx, float v) {
  if (MODE == 0) {
    ((float*)outp)[oidx] = v;
  } else if (MODE == 1) {
    ((unsigned short*)outp)[oidx] = f2bf(v);
  } else if (MODE == 2) {
    ((float*)outp)[oidx] = v + ((const float*)aux)[oidx];
  } else {
    float gt = bf2f(((const unsigned short*)aux)[oidx]);
    float sg = gt / (1.f + __expf(-gt));
    ((unsigned short*)outp)[oidx] = f2bf(sg * v);
  }
}

// ---------------------------------------------------------------------------
// 128x128 GEMM, 4 waves, 32 KB LDS, 3 blocks/CU (9.9 TB/s staging).
// Best when A streams (down-proj: A = 77.6 MB ACT).
// ---------------------------------------------------------------------------
template<int MODE, bool BIAS>
__global__ __launch_bounds__(256)
void gemm_bf(const unsigned short* __restrict__ A, int lda,
             const unsigned short* __restrict__ W,
             const float* __restrict__ bias,
             void* __restrict__ outp, int ldo, int col0,
             const void* __restrict__ aux, int K)
{
  const int g  = xcd_remap(blockIdx.x, gridDim.x);
  const int mb = g & 15;
  const int nb = g >> 4;
  const int t = threadIdx.x;
  const int w = t >> 6, l = t & 63, lg = l >> 4, lc = l & 15;
  const int wr = w >> 1, wc = w & 1;

  __shared__ __align__(16) unsigned short As[128 * 64];
  __shared__ __align__(16) unsigned short Ws[128 * 64];

  floatx4 acc[4][4] = {};

  const char* Ablk = (const char*)(A + (size_t)mb * 128 * lda);
  const char* Wblk = (const char*)(W + (size_t)nb * 128 * K);

  const int s_row = t >> 3;
  const int s_scb = (((t & 7) ^ ((t >> 3) & 7)) << 4);
  const int r_sw  = (lc & 7) << 4;

  const size_t abytes = (size_t)lda * 2;
  const size_t wbytes = (size_t)K * 2;
  const int nk = K >> 6;
  for (int kt = 0; kt < nk; ++kt) {
    #pragma unroll
    for (int i = 0; i < 4; ++i)
      gload_lds16(Ablk + (size_t)(i * 32 + s_row) * abytes + (size_t)kt * 128 + s_scb,
                  (char*)As + i * 4096 + t * 16);
    #pragma unroll
    for (int i = 0; i < 4; ++i)
      gload_lds16(Wblk + (size_t)(i * 32 + s_row) * wbytes + (size_t)kt * 128 + s_scb,
                  (char*)Ws + i * 4096 + t * 16);
    __syncthreads();
    #pragma unroll
    for (int kk = 0; kk < 2; ++kk) {
      short8 afr[4], bfr[4];
      #pragma unroll
      for (int m = 0; m < 4; ++m)
        afr[m] = *(const short8*)((const char*)As + (wr*64 + m*16 + lc) * 128
                                 + ((kk*64 + lg*16) ^ r_sw));
      #pragma unroll
      for (int n = 0; n < 4; ++n)
        bfr[n] = *(const short8*)((const char*)Ws + (wc*64 + n*16 + lc) * 128
                                  + ((kk*64 + lg*16) ^ r_sw));
      #pragma unroll
      for (int m = 0; m < 4; ++m)
        #pragma unroll
        for (int n = 0; n < 4; ++n)
          acc[m][n] = __builtin_amdgcn_mfma_f32_16x16x32_bf16(afr[m], bfr[n], acc[m][n], 0, 0, 0);
    }
    __syncthreads();
  }

  float bv[4] = {0.f, 0.f, 0.f, 0.f};
  if (BIAS) {
    #pragma unroll
    for (int n = 0; n < 4; ++n) bv[n] = bias[nb*128 + wc*64 + n*16 + lc];
  }
  #pragma unroll
  for (int m = 0; m < 4; ++m) {
    #pragma unroll
    for (int n = 0; n < 4; ++n) {
      const int colg = col0 + nb*128 + wc*64 + n*16 + lc;
      #pragma unroll
      for (int j = 0; j < 4; ++j) {
        const int rowg = mb*128 + wr*64 + m*16 + lg*4 + j;
        store_out(MODE, outp, aux, (size_t)rowg * ldo + colg, acc[m][n][j] + bv[n]);
      }
    }
  }
}

// ---------------------------------------------------------------------------
// 256(M)x128(N) GEMM, 4 waves, 48 KB LDS, 2 blocks/CU (8.8 TB/s) with 25%
// fewer staged bytes. Best when A is cache-resident (QKV, O, gate, up).
// ---------------------------------------------------------------------------
template<int MODE, bool BIAS>
__global__ __launch_bounds__(256, 2)
void gemm_w(const unsigned short* __restrict__ A, int lda,
            const unsigned short* __restrict__ W,
            const float* __restrict__ bias,
            void* __restrict__ outp, int ldo, int col0,
            const void* __restrict__ aux, int K)
{
  const int g  = xcd_remap(blockIdx.x, gridDim.x);
  const int mb = g & 7;
  const int nb = g >> 3;
  const int t  = threadIdx.x;
  const int w  = t >> 6, l = t & 63, lg = l >> 4, lc = l & 15;
  const int wr = w >> 1, wc = w & 1;

  __shared__ __align__(16) unsigned short As[256 * 64];
  __shared__ __align__(16) unsigned short Bs[128 * 64];

  floatx4 acc[8][4] = {};

  const char* Ablk = (const char*)(A + (size_t)mb * 256 * lda);
  const char* Wblk = (const char*)(W + (size_t)nb * 128 * K);

  const int s_row = t >> 3;
  const int s_scb = (((t & 7) ^ ((t >> 3) & 7)) << 4);
  const int r_sw  = (lc & 7) << 4;

  const size_t abytes = (size_t)lda * 2;
  const size_t wbytes = (size_t)K * 2;
  const int nk = K >> 6;

  for (int kt = 0; kt < nk; ++kt) {
    const char* asrc = Ablk + (size_t)kt * 128 + s_scb;
    #pragma unroll
    for (int i = 0; i < 8; ++i)
      gload_lds16(asrc + (size_t)(i * 32 + s_row) * abytes,
                  (char*)As + i * 4096 + t * 16);
    const char* wsrc = Wblk + (size_t)kt * 128 + s_scb;
    #pragma unroll
    for (int i = 0; i < 4; ++i)
      gload_lds16(wsrc + (size_t)(i * 32 + s_row) * wbytes,
                  (char*)Bs + i * 4096 + t * 16);
    __syncthreads();
    #pragma unroll
    for (int kk = 0; kk < 2; ++kk) {
      const int ko = (kk * 64 + lg * 16) ^ r_sw;
      short8 bfr[4];
      #pragma unroll
      for (int n = 0; n < 4; ++n)
        bfr[n] = *(const short8*)((const char*)Bs + (wc*64 + n*16 + lc) * 128 + ko);
      #pragma unroll
      for (int m = 0; m < 8; ++m) {
        short8 af = *(const short8*)((const char*)As + (wr*128 + m*16 + lc) * 128 + ko);
        #pragma unroll
        for (int n = 0; n < 4; ++n)
          acc[m][n] = __builtin_amdgcn_mfma_f32_16x16x32_bf16(af, bfr[n], acc[m][n], 0, 0, 0);
      }
    }
    __syncthreads();
  }

  float bv[4] = {0.f, 0.f, 0.f, 0.f};
  if (BIAS) {
    #pragma unroll
    for (int n = 0; n < 4; ++n) bv[n] = bias[nb*128 + wc*64 + n*16 + lc];
  }
  #pragma unroll
  for (int m = 0; m < 8; ++m) {
    #pragma unroll
    for (int n = 0; n < 4; ++n) {
      const int colg = col0 + nb*128 + wc*64 + n*16 + lc;
      #pragma unroll
      for (int j = 0; j < 4; ++j) {
        const int rowg = mb*256 + wr*128 + m*16 + lg*4 + j;
        store_out(MODE, outp, aux, (size_t)rowg * ldo + colg, acc[m][n][j] + bv[n]);
      }
    }
  }
}

// ---------------------------------------------------------------------------
__global__ __launch_bounds__(256)
void cvt_bf16_kernel(const float* __restrict__ in, unsigned short* __restrict__ out, int n8)
{
  int i = blockIdx.x * 256 + threadIdx.x;
  const int stride = gridDim.x * 256;
  for (; i < n8; i += stride) {
    floatx4 a = *(const floatx4*)(in + (size_t)i * 8);
    floatx4 b = *(const floatx4*)(in + (size_t)i * 8 + 4);
    uint4v p;
    p[0] = pk2(a[0], a[1]); p[1] = pk2(a[2], a[3]);
    p[2] = pk2(b[0], b[1]); p[3] = pk2(b[2], b[3]);
    *(uint4v*)(out + (size_t)i * 8) = p;
  }
}

__global__ void pack_bias_kernel(const float* __restrict__ qb, const float* __restrict__ kb,
                                 const float* __restrict__ vb, float* __restrict__ o)
{
  int i = blockIdx.x * 256 + threadIdx.x;   // 4608
  if (i < 3584) o[i] = qb[i];
  else if (i < 4096) o[i] = kb[i - 3584];
  else if (i < 4608) o[i] = vb[i - 4096];
}

// ---------------------------------------------------------------------------
__global__ __launch_bounds__(448)
void rmsnorm_kernel(const float* __restrict__ x, const float* __restrict__ wgt,
                    unsigned short* __restrict__ out)
{
  const int row = blockIdx.x, t = threadIdx.x;
  const float* xp = x + (size_t)row * HDIM + t * 8;
  floatx4 a = *(const floatx4*)xp;
  floatx4 b = *(const floatx4*)(xp + 4);
  float ss = a[0]*a[0]+a[1]*a[1]+a[2]*a[2]+a[3]*a[3]
           + b[0]*b[0]+b[1]*b[1]+b[2]*b[2]+b[3]*b[3];
  #pragma unroll
  for (int mk = 1; mk < 64; mk <<= 1) ss += __shfl_xor(ss, mk, 64);
  __shared__ float wsum[8];
  if ((t & 63) == 0) wsum[t >> 6] = ss;
  __syncthreads();
  float tot = 0.f;
  #pragma unroll
  for (int i = 0; i < 7; ++i) tot += wsum[i];
  const float sc = rsqrtf(tot * (1.f / 3584.f) + 1e-6f);
  const float* wp = wgt + t * 8;
  short8 o;
  #pragma unroll
  for (int e = 0; e < 4; ++e) o[e]   = (short)f2bf(a[e] * sc * wp[e]);
  #pragma unroll
  for (int e = 0; e < 4; ++e) o[4+e] = (short)f2bf(b[e] * sc * wp[4+e]);
  *(short8*)(out + (size_t)row * HDIM + t * 8) = o;
}

// ---------------------------------------------------------------------------
__global__ void rope_table_kernel(const int* __restrict__ pos, float* __restrict__ tab)
{
  int idx = blockIdx.x * 256 + threadIdx.x;
  int s = idx >> 6, d = idx & 63;
  float p = (float)pos[s];
  float inv = expf(-((float)(2 * d) * (1.f / 128.f)) * 13.815510557964274f);
  float ang = p * inv;
  tab[idx] = cosf(ang);
  tab[S_LEN * 64 + idx] = sinf(ang);
}

template<int NHX>
__global__ void rope_apply_kernel(const float* __restrict__ in, const float* __restrict__ tab,
                                  unsigned short* __restrict__ out, int col0)
{
  int idx = blockIdx.x * 256 + threadIdx.x;
  int d = idx & 63;
  int rem = idx >> 6;
  int hh = rem % NHX;
  int s  = rem / NHX;
  const float* ip = in + (size_t)s * 4608 + col0 + hh * HDHD;
  float x1 = ip[d], x2 = ip[64 + d];
  float c  = tab[s * 64 + d];
  float sn = tab[S_LEN * 64 + s * 64 + d];
  unsigned short* op = out + (size_t)s * (NHX * HDHD) + hh * HDHD;
  op[d]      = f2bf(x1 * c - x2 * sn);
  op[64 + d] = f2bf(x2 * c + x1 * sn);
}

__global__ void vtrans_kernel(const float* __restrict__ qkvf, unsigned short* __restrict__ vt)
{
  int idx = blockIdx.x * 256 + threadIdx.x;
  int s = idx & (S_LEN - 1);
  int c = idx >> 11;
  vt[idx] = f2bf(qkvf[(size_t)s * 4608 + 4096 + c]);
}

// ---------------------------------------------------------------------------
// Flash attention QBLK=128, 512 threads / 8 waves (R10-proven).
// ---------------------------------------------------------------------------
__global__ __launch_bounds__(512)
void attn_kernel(const unsigned short* __restrict__ Q,
                 const unsigned short* __restrict__ Kr,
                 const unsigned short* __restrict__ Vt,
                 unsigned short* __restrict__ O)
{
  const int g  = xcd_remap(blockIdx.x, gridDim.x);   // grid 448
  const int qb = g & 15;
  const int h  = g >> 4;
  const int kvh = h / 7;
  const int t = threadIdx.x, w = t >> 6, l = t & 63, lg = l >> 4, lc = l & 15;

  __shared__ __align__(16) unsigned short Ks[64 * 128];
  __shared__ __align__(16) unsigned short Vs[128 * 64];
  __shared__ __align__(16) unsigned short Ps[8][16 * 64];

  const int qrow = qb * 128 + w * 16 + lc;
  short8 qf[4];
  {
    const unsigned short* qp = Q + (size_t)qrow * HDIM + h * HDHD + lg * 8;
    #pragma unroll
    for (int kk = 0; kk < 4; ++kk) qf[kk] = *(const short8*)(qp + kk * 32);
  }

  float mrun[4], lrun[4];
  #pragma unroll
  for (int j = 0; j < 4; ++j) { mrun[j] = -1e30f; lrun[j] = 0.f; }
  floatx4 oacc[8] = {};

  const int k_row = t >> 4;
  const int k_scb = (((t & 15) ^ ((t >> 4) & 7)) << 4);
  const int v_row = t >> 3;
  const int v_scb = (((t & 7) ^ ((t >> 3) & 7)) << 4);
  const int r_sw  = (lc & 7) << 4;
  const float scale = 0.08838834764831843f;

  for (int kt = 0; kt < 32; ++kt) {
    #pragma unroll
    for (int i = 0; i < 2; ++i)
      gload_lds16((const char*)Kr + ((size_t)(kt*64 + i*32 + k_row) * 512 + kvh*128) * 2 + k_scb,
                  (char*)Ks + i * 8192 + t * 16);
    #pragma unroll
    for (int i = 0; i < 2; ++i)
      gload_lds16((const char*)Vt + ((size_t)(kvh*128 + i*64 + v_row) * S_LEN) * 2
                      + (size_t)kt * 128 + v_scb,
                  (char*)Vs + i * 8192 + t * 16);
    __syncthreads();

    floatx4 sacc[4] = {};
    #pragma unroll
    for (int kk = 0; kk < 4; ++kk) {
      #pragma unroll
      for (int n = 0; n < 4; ++n) {
        short8 kf = *(const short8*)((const char*)Ks + (n*16 + lc) * 256
                                     + ((kk*64 + lg*16) ^ r_sw));
        sacc[n] = __builtin_amdgcn_mfma_f32_16x16x32_bf16(qf[kk], kf, sacc[n], 0, 0, 0);
      }
    }

    float pv[4][4], mt[4];
    #pragma unroll
    for (int j = 0; j < 4; ++j) {
      float a0 = sacc[0][j]*scale, a1 = sacc[1][j]*scale;
      float a2 = sacc[2][j]*scale, a3 = sacc[3][j]*scale;
      pv[0][j]=a0; pv[1][j]=a1; pv[2][j]=a2; pv[3][j]=a3;
      mt[j] = fmaxf(fmaxf(a0, a1), fmaxf(a2, a3));
    }
    #pragma unroll
    for (int mk = 1; mk < 16; mk <<= 1)
      #pragma unroll
      for (int j = 0; j < 4; ++j)
        mt[j] = fmaxf(mt[j], __shfl_xor(mt[j], mk, 16));

    float corr[4], rs[4];
    #pragma unroll
    for (int j = 0; j < 4; ++j) {
      float mn = fmaxf(mrun[j], mt[j]);
      corr[j] = __expf(mrun[j] - mn);
      mrun[j] = mn;
      rs[j] = 0.f;
    }
    #pragma unroll
    for (int n = 0; n < 4; ++n)
      #pragma unroll
      for (int j = 0; j < 4; ++j) {
        float p = __expf(pv[n][j] - mrun[j]);
        pv[n][j] = p; rs[j] += p;
      }
    #pragma unroll
    for (int mk = 1; mk < 16; mk <<= 1)
      #pragma unroll
      for (int j = 0; j < 4; ++j)
        rs[j] += __shfl_xor(rs[j], mk, 16);
    #pragma unroll
    for (int j = 0; j < 4; ++j) lrun[j] = lrun[j] * corr[j] + rs[j];
    #pragma unroll
    for (int q = 0; q < 8; ++q) {
      oacc[q][0] *= corr[0]; oacc[q][1] *= corr[1];
      oacc[q][2] *= corr[2]; oacc[q][3] *= corr[3];
    }

    char* pw = (char*)Ps[w];
    #pragma unroll
    for (int n = 0; n < 4; ++n)
      #pragma unroll
      for (int j = 0; j < 4; ++j) {
        const int prow = lg*4 + j;
        *(unsigned short*)(pw + prow*128 + ((((n*16 + lc)*2)) ^ ((prow & 7) << 4)))
            = f2bf(pv[n][j]);
      }

    short8 pa[2];
    #pragma unroll
    for (int ks = 0; ks < 2; ++ks)
      pa[ks] = *(const short8*)(pw + lc*128 + ((ks*64 + lg*16) ^ r_sw));
    #pragma unroll
    for (int ks = 0; ks < 2; ++ks)
      #pragma unroll
      for (int q = 0; q < 8; ++q) {
        short8 vf = *(const short8*)((const char*)Vs + (q*16 + lc) * 128
                                     + ((ks*64 + lg*16) ^ r_sw));
        oacc[q] = __builtin_amdgcn_mfma_f32_16x16x32_bf16(pa[ks], vf, oacc[q], 0, 0, 0);
      }
    __syncthreads();
  }

  float invl[4];
  #pragma unroll
  for (int j = 0; j < 4; ++j) invl[j] = 1.f / lrun[j];
  #pragma unroll
  for (int q = 0; q < 8; ++q)
    #pragma unroll
    for (int j = 0; j < 4; ++j) {
      int rowg = qb*128 + w*16 + lg*4 + j;
      int colg = h*HDHD + q*16 + lc;
      O[(size_t)rowg * HDIM + colg] = f2bf(oacc[q][j] * invl[j]);
    }
}

__global__ void sentinel_kernel(float* out, int n) {
  int i = blockIdx.x * 256 + threadIdx.x;
  if (i < n) out[i] = 1.0e6f;
}

// ---------------------------------------------------------------------------
extern "C" void kernel_launch(void* const* d_in, const int* in_sizes, int n_in,
                              void* d_out, int out_size, void* d_ws, size_t ws_size,
                              hipStream_t stream)
{
  (void)in_sizes; (void)n_in;
  const float* hidden = (const float*)d_in[0];
  const int*   pos    = (const int*)d_in[1];
  const float* q_w    = (const float*)d_in[2];
  const float* q_b    = (const float*)d_in[3];
  const float* k_w    = (const float*)d_in[4];
  const float* k_b    = (const float*)d_in[5];
  const float* v_w    = (const float*)d_in[6];
  const float* v_b    = (const float*)d_in[7];
  const float* o_w    = (const float*)d_in[8];
  const float* gate_w = (const float*)d_in[9];
  const float* up_w   = (const float*)d_in[10];
  const float* down_w = (const float*)d_in[11];
  const float* ln1    = (const float*)d_in[12];
  const float* ln2    = (const float*)d_in[13];
  float* out = (float*)d_out;
  char* ws = (char*)d_ws;

  unsigned short* XN    = (unsigned short*)(ws + 0);          // S*H bf16
  float*          QKVF  = (float*)(ws + 14680064);            // S*4608 f32
  unsigned short* QR    = (unsigned short*)(ws + 52428800);   // S*3584 bf16
  unsigned short* KR    = (unsigned short*)(ws + 67108864);   // S*512 bf16
  unsigned short* VT    = (unsigned short*)(ws + 69206016);   // 512*S bf16
  float*          ROPET = (float*)(ws + 71303168);            // S*128 f32
  float*          BQKV  = (float*)(ws + 72351744);            // 4608 f32
  unsigned short* CTX   = (unsigned short*)(ws + 77594624);   // S*H bf16
  unsigned short* GBUF  = (unsigned short*)(ws + 0);          // S*I bf16 (phase 2)
  unsigned short* ACT   = (unsigned short*)(ws + 77594624);   // S*I bf16 (phase 2)
  float*          H1    = (float*)(ws + 155189248);           // S*H f32
  unsigned short* XN2   = (unsigned short*)(ws + 184549376);  // S*H bf16
  unsigned short* WB    = (unsigned short*)(ws + 199229440);  // 18944*3584 bf16 (reused)
  const size_t NEED_BIG = 199229440 + 135790592;              // 335,020,032

  if (ws_size < NEED_BIG) {
    sentinel_kernel<<<(out_size + 255) / 256, 256, 0, stream>>>(out, out_size);
    return;
  }

  const int CVG = 2048;

  rope_table_kernel<<<(S_LEN * 64) / 256, 256, 0, stream>>>(pos, ROPET);
  rmsnorm_kernel<<<S_LEN, 448, 0, stream>>>(hidden, ln1, XN);

  pack_bias_kernel<<<18, 256, 0, stream>>>(q_b, k_b, v_b, BQKV);
  cvt_bf16_kernel<<<CVG, 256, 0, stream>>>(q_w, WB,               (3584 * 3584) / 8);
  cvt_bf16_kernel<<<CVG, 256, 0, stream>>>(k_w, WB + 3584 * 3584, (512 * 3584) / 8);
  cvt_bf16_kernel<<<CVG, 256, 0, stream>>>(v_w, WB + 4096 * 3584, (512 * 3584) / 8);

  // QKV: [2048,4608]  gemm_w 8x36 = 288 blocks
  gemm_w<0, true><<<288, 256, 0, stream>>>(XN, HDIM, WB, BQKV, QKVF, 4608, 0, nullptr, HDIM);

  rope_apply_kernel<28><<<(S_LEN * 28 * 64) / 256, 256, 0, stream>>>(QKVF, ROPET, QR, 0);
  rope_apply_kernel<4><<<(S_LEN * 4 * 64) / 256,  256, 0, stream>>>(QKVF, ROPET, KR, 3584);
  vtrans_kernel<<<(512 * S_LEN) / 256, 256, 0, stream>>>(QKVF, VT);

  cvt_bf16_kernel<<<CVG, 256, 0, stream>>>(o_w, WB, (3584 * 3584) / 8);

  // attention: QBLK=128, 512 threads, 448 blocks
  attn_kernel<<<448, 512, 0, stream>>>(QR, KR, VT, CTX);

  // O-proj fused with residual: H1 = CTX*o_w^T + hidden  (gemm_w MODE 2)
  gemm_w<2, false><<<224, 256, 0, stream>>>(CTX, HDIM, WB, nullptr, H1, HDIM, 0, hidden, HDIM);
  rmsnorm_kernel<<<S_LEN, 448, 0, stream>>>(H1, ln2, XN2);

  // gate: [2048,18944]  gemm_w 148x8 = 1184 blocks
  cvt_bf16_kernel<<<CVG, 256, 0, stream>>>(gate_w, WB, (IDIM * HDIM) / 8);
  gemm_w<1, false><<<1184, 256, 0, stream>>>(XN2, HDIM, WB, nullptr, GBUF, IDIM, 0, nullptr, HDIM);

  // up + swiglu: [2048,18944]  gemm_w
  cvt_bf16_kernel<<<CVG, 256, 0, stream>>>(up_w, WB, (IDIM * HDIM) / 8);
  gemm_w<3, false><<<1184, 256, 0, stream>>>(XN2, HDIM, WB, nullptr, ACT, IDIM, 0, GBUF, HDIM);

  // down + residual: [2048,3584], K=18944  gemm_bf 448 blocks
  cvt_bf16_kernel<<<CVG, 256, 0, stream>>>(down_w, WB, (HDIM * IDIM) / 8);
  gemm_bf<2, false><<<448, 256, 0, stream>>>(ACT, IDIM, WB, nullptr, out, HDIM, 0, H1, IDIM);
}